// Round 4
// baseline (582.361 us; speedup 1.0000x reference)
//
#include <hip/hip_runtime.h>
#include <hip/hip_bf16.h>

#define BATCH 16
#define NH    8
#define CH    8
#define HH    56
#define WW    56
#define POS   3136          // 56*56 = 49*64
#define QKVC  192
#define OC    64
#define SCALE 0.17677669529663687f   // 32^-0.5

typedef __attribute__((ext_vector_type(8))) short bf16x8;   // 8 bf16 = 4 VGPRs
typedef __attribute__((ext_vector_type(4))) float f32x4;

__device__ __forceinline__ unsigned short f2b(float f) {
    __hip_bfloat16 h = __float2bfloat16(f);
    union { __hip_bfloat16 h; unsigned short u; } c; c.h = h; return c.u;
}
__device__ __forceinline__ unsigned int pk(float lo, float hi) {
    return (unsigned int)f2b(lo) | ((unsigned int)f2b(hi) << 16);
}

// ---------------------------------------------------------------------------
// Kernel A: qkv = x @ qkv_w^T + qkv_b via bf16 MFMA, f[b][o][pos] fp32.
// Mtile=64 (49*64=3136 exact), Ntile=96, K=256 in 8 steps of 32.
// A staged with in-LDS transpose (pack 2 c-rows per 4B write, 2-way banks).
// grid (49, 2, 16), 256 thr.
// ---------------------------------------------------------------------------
__global__ __launch_bounds__(256) void qkv_mfma(const float* __restrict__ x,
                                                const float* __restrict__ w,
                                                const float* __restrict__ bias,
                                                float* __restrict__ f) {
    __shared__ __align__(16) unsigned short wa[64 * 40];    // [m][k] rowstride 40 (80B)
    __shared__ __align__(16) unsigned short wb[96 * 264];   // [n][k] rowstride 264 (528B)
    const int tid = threadIdx.x;
    const int p0  = blockIdx.x * 64;
    const int o0  = blockIdx.y * 96;
    const int b   = blockIdx.z;

    // stage B once: w[o0+o][c], 96x256 fp32 -> bf16
    for (int idx = tid; idx < 96 * 64; idx += 256) {
        int o  = idx >> 6;
        int c4 = (idx & 63) << 2;
        const float4 t = *(const float4*)(w + (size_t)(o0 + o) * 256 + c4);
        *(unsigned int*)&wb[o * 264 + c4]     = pk(t.x, t.y);
        *(unsigned int*)&wb[o * 264 + c4 + 2] = pk(t.z, t.w);
    }

    f32x4 acc[6];
    #pragma unroll
    for (int u = 0; u < 6; ++u) acc[u] = (f32x4){0.f, 0.f, 0.f, 0.f};

    const int lane = tid & 63;
    const int wid  = tid >> 6;          // wave 0..3
    const int m0   = wid * 16;
    const int ml   = lane & 15;
    const int kg   = lane >> 4;         // 0..3

    const int c2 = (tid & 15) * 2;      // c-pair within k-step
    const int p4 = (tid >> 4) * 4;      // 4 pos per thread (tid>>4 in 0..15)
    const float* xb = x + (size_t)b * 256 * POS;

    for (int ks = 0; ks < 8; ++ks) {
        const int c0 = ks * 32;
        __syncthreads();
        // stage A: transpose x[c0..c0+31][p0..p0+63] -> wa[p][c_local] bf16
        {
            const float4 r0 = *(const float4*)(xb + (size_t)(c0 + c2)     * POS + p0 + p4);
            const float4 r1 = *(const float4*)(xb + (size_t)(c0 + c2 + 1) * POS + p0 + p4);
            *(unsigned int*)&wa[(p4 + 0) * 40 + c2] = pk(r0.x, r1.x);
            *(unsigned int*)&wa[(p4 + 1) * 40 + c2] = pk(r0.y, r1.y);
            *(unsigned int*)&wa[(p4 + 2) * 40 + c2] = pk(r0.z, r1.z);
            *(unsigned int*)&wa[(p4 + 3) * 40 + c2] = pk(r0.w, r1.w);
        }
        __syncthreads();
        // A frag: A[m=ml][k=kg*8+j], 16B contiguous
        bf16x8 af = *(const bf16x8*)&wa[(m0 + ml) * 40 + kg * 8];
        #pragma unroll
        for (int u = 0; u < 6; ++u) {
            bf16x8 bf = *(const bf16x8*)&wb[(u * 16 + ml) * 264 + c0 + kg * 8];
            acc[u] = __builtin_amdgcn_mfma_f32_16x16x32_bf16(af, bf, acc[u], 0, 0, 0);
        }
    }

    // epilogue: D row=(kg*4+r)=pos offset, col=ml=o offset
    #pragma unroll
    for (int u = 0; u < 6; ++u) {
        int o = o0 + u * 16 + ml;
        float bj = bias[o];
        float4 st = { acc[u][0] + bj, acc[u][1] + bj, acc[u][2] + bj, acc[u][3] + bj };
        *(float4*)(f + ((size_t)b * QKVC + o) * POS + p0 + m0 + kg * 4) = st;
    }
}

// ---------------------------------------------------------------------------
// Kernel B: slide attention (fp32 math, unchanged), output aT[b][pos][64] bf16
// grid (7, 8, 16), 448 thr.
// ---------------------------------------------------------------------------
#define TBH 8
__global__ __launch_bounds__(448) void attn_kernel(const float* __restrict__ f,
                                                   const float* __restrict__ dc_b,
                                                   const float* __restrict__ dc1_w,
                                                   const float* __restrict__ dc1_b,
                                                   const float* __restrict__ rpb,
                                                   unsigned short* __restrict__ aT) {
    __shared__ float kbuf[CH][TBH + 2][WW + 2];
    __shared__ float vbuf[CH][TBH + 2][WW + 2];
    __shared__ float wcp[CH * 9 * 12];

    const int tid = threadIdx.x;
    const int ty0 = blockIdx.x * TBH;
    const int h   = blockIdx.y;
    const int b   = blockIdx.z;
    const float* fb = f + ((size_t)b * QKVC + h * 24) * POS;

    const int HALO = (TBH + 2) * (WW + 2);   // 580
    for (int idx = tid; idx < 16 * HALO; idx += 448) {
        int c16 = idx / HALO;
        int rem = idx - c16 * HALO;
        int row = rem / (WW + 2);
        int col = rem - row * (WW + 2);
        int gy = ty0 + row - 1;
        int gx = col - 1;
        float val = 0.f;
        if (gy >= 0 && gy < HH && gx >= 0 && gx < WW) {
            int ch = c16 & 7;
            int o  = (c16 < 8) ? (8 + ch) : (16 + ch);
            val = fb[o * POS + gy * WW + gx];
        }
        float* dst = (c16 < 8) ? &kbuf[c16 & 7][0][0] : &vbuf[c16 & 7][0][0];
        dst[rem] = val;
    }
    for (int idx = tid; idx < 72; idx += 448) {
        int base = idx * 12;
        #pragma unroll
        for (int j = 0; j < 9; ++j) wcp[base + j] = dc1_w[idx * 9 + j];
        float db = dc_b[idx] + dc1_b[idx];
        int ka = idx % 9;
        wcp[base + 9]  = db + rpb[h * 9 + ka];
        wcp[base + 10] = db;
        wcp[base + 11] = 0.f;
    }
    __syncthreads();

    const int ly  = tid / WW;
    const int lx  = tid - ly * WW;
    const int pos = (ty0 + ly) * WW + lx;

    float q[CH];
    #pragma unroll
    for (int ch = 0; ch < CH; ++ch) q[ch] = fb[ch * POS + pos] * SCALE;

    float logits[9];
    #pragma unroll
    for (int ka = 0; ka < 9; ++ka) logits[ka] = 0.f;
    #pragma unroll
    for (int ch = 0; ch < CH; ++ch) {
        float n[9];
        #pragma unroll
        for (int dy = 0; dy < 3; ++dy)
            #pragma unroll
            for (int dx = 0; dx < 3; ++dx)
                n[dy * 3 + dx] = kbuf[ch][ly + dy][lx + dx];
        float qc = q[ch];
        const float4* wp = (const float4*)&wcp[ch * 108];
        #pragma unroll
        for (int ka = 0; ka < 9; ++ka) {
            float4 a4 = wp[ka * 3 + 0];
            float4 b4 = wp[ka * 3 + 1];
            float4 c4 = wp[ka * 3 + 2];
            float kv = n[ka] + c4.y;
            kv += n[0]*a4.x + n[1]*a4.y + n[2]*a4.z + n[3]*a4.w;
            kv += n[4]*b4.x + n[5]*b4.y + n[6]*b4.z + n[7]*b4.w;
            kv += n[8]*c4.x;
            logits[ka] += qc * kv;
        }
    }

    float m = logits[0];
    #pragma unroll
    for (int ka = 1; ka < 9; ++ka) m = fmaxf(m, logits[ka]);
    float att[9];
    float s = 0.f;
    #pragma unroll
    for (int ka = 0; ka < 9; ++ka) { att[ka] = __expf(logits[ka] - m); s += att[ka]; }
    float inv = 1.f / s;
    #pragma unroll
    for (int ka = 0; ka < 9; ++ka) att[ka] *= inv;

    float outv[CH];
    #pragma unroll
    for (int ch = 0; ch < CH; ++ch) {
        float n[9];
        #pragma unroll
        for (int dy = 0; dy < 3; ++dy)
            #pragma unroll
            for (int dx = 0; dx < 3; ++dx)
                n[dy * 3 + dx] = vbuf[ch][ly + dy][lx + dx];
        const float4* wp = (const float4*)&wcp[ch * 108];
        float o = 0.f;
        #pragma unroll
        for (int ka = 0; ka < 9; ++ka) {
            float4 a4 = wp[ka * 3 + 0];
            float4 b4 = wp[ka * 3 + 1];
            float4 c4 = wp[ka * 3 + 2];
            float vv = n[ka] + c4.z;
            vv += n[0]*a4.x + n[1]*a4.y + n[2]*a4.z + n[3]*a4.w;
            vv += n[4]*b4.x + n[5]*b4.y + n[6]*b4.z + n[7]*b4.w;
            vv += n[8]*c4.x;
            o += att[ka] * vv;
        }
        outv[ch] = o;
    }

    // aT[b][pos][h*8..h*8+7] bf16, one 16B store
    uint4 st = { pk(outv[0], outv[1]), pk(outv[2], outv[3]),
                 pk(outv[4], outv[5]), pk(outv[6], outv[7]) };
    *(uint4*)(aT + ((size_t)(b * POS + pos)) * 64 + h * 8) = st;
}

// ---------------------------------------------------------------------------
// Kernel C: out = a @ proj_w^T + proj_b via bf16 MFMA, fp32 NCHW out.
// Mtile=64, Ntile=128, K=64 (staged whole, 2 mfma k-steps). grid (49, 2, 16)
// ---------------------------------------------------------------------------
__global__ __launch_bounds__(256) void proj_mfma(const unsigned short* __restrict__ aT,
                                                 const float* __restrict__ w,
                                                 const float* __restrict__ bias,
                                                 float* __restrict__ out) {
    __shared__ __align__(16) unsigned short wa[64 * 72];    // [m][k] rowstride 72 (144B)
    __shared__ __align__(16) unsigned short wb[128 * 72];   // [n][k]
    const int tid = threadIdx.x;
    const int p0  = blockIdx.x * 64;
    const int o0  = blockIdx.y * 128;
    const int b   = blockIdx.z;

    // stage A: 64 rows x 128B (already bf16, k-contiguous)
    for (int idx = tid; idx < 512; idx += 256) {
        int m = idx >> 3, qq = idx & 7;
        uint4 v = *(const uint4*)(aT + ((size_t)(b * POS + p0 + m) * 64 + qq * 8));
        *(uint4*)&wa[m * 72 + qq * 8] = v;
    }
    // stage B: proj_w[o0+o][ch] 128x64 fp32 -> bf16
    for (int idx = tid; idx < 2048; idx += 256) {
        int o = idx >> 4, c4 = (idx & 15) << 2;
        const float4 t = *(const float4*)(w + (size_t)(o0 + o) * 64 + c4);
        *(unsigned int*)&wb[o * 72 + c4]     = pk(t.x, t.y);
        *(unsigned int*)&wb[o * 72 + c4 + 2] = pk(t.z, t.w);
    }
    __syncthreads();

    const int lane = tid & 63;
    const int wid  = tid >> 6;
    const int m0   = wid * 16;
    const int ml   = lane & 15;
    const int kg   = lane >> 4;

    f32x4 acc[8];
    #pragma unroll
    for (int u = 0; u < 8; ++u) acc[u] = (f32x4){0.f, 0.f, 0.f, 0.f};

    #pragma unroll
    for (int s = 0; s < 2; ++s) {
        bf16x8 af = *(const bf16x8*)&wa[(m0 + ml) * 72 + s * 32 + kg * 8];
        #pragma unroll
        for (int u = 0; u < 8; ++u) {
            bf16x8 bf = *(const bf16x8*)&wb[(u * 16 + ml) * 72 + s * 32 + kg * 8];
            acc[u] = __builtin_amdgcn_mfma_f32_16x16x32_bf16(af, bf, acc[u], 0, 0, 0);
        }
    }

    #pragma unroll
    for (int u = 0; u < 8; ++u) {
        int o = o0 + u * 16 + ml;
        float bj = bias[o];
        float4 st = { acc[u][0] + bj, acc[u][1] + bj, acc[u][2] + bj, acc[u][3] + bj };
        *(float4*)(out + ((size_t)b * 256 + o) * POS + p0 + m0 + kg * 4) = st;
    }
}

// ---------------------------------------------------------------------------
extern "C" void kernel_launch(void* const* d_in, const int* in_sizes, int n_in,
                              void* d_out, int out_size, void* d_ws, size_t ws_size,
                              hipStream_t stream) {
    const float* x      = (const float*)d_in[0];
    const float* qkv_w  = (const float*)d_in[1];
    const float* qkv_b  = (const float*)d_in[2];
    const float* dc_b   = (const float*)d_in[3];
    const float* dc1_w  = (const float*)d_in[4];
    const float* dc1_b  = (const float*)d_in[5];
    const float* rpb    = (const float*)d_in[6];
    const float* proj_w = (const float*)d_in[7];
    const float* proj_b = (const float*)d_in[8];
    float* out = (float*)d_out;

    // ws: f fp32 38.5 MB + aT bf16 6.4 MB
    float* f = (float*)d_ws;
    unsigned short* aT = (unsigned short*)(f + (size_t)BATCH * QKVC * POS);

    qkv_mfma<<<dim3(49, 2, BATCH), 256, 0, stream>>>(x, qkv_w, qkv_b, f);
    attn_kernel<<<dim3(7, NH, BATCH), 448, 0, stream>>>(f, dc_b, dc1_w, dc1_b, rpb, aT);
    proj_mfma<<<dim3(49, 2, BATCH), 256, 0, stream>>>(aT, proj_w, proj_b, out);
}

// Round 5
// 225.310 us; speedup vs baseline: 2.5847x; 2.5847x over previous
//
#include <hip/hip_runtime.h>
#include <hip/hip_bf16.h>

#define BATCH 16
#define NH    8
#define CH    8
#define HH    56
#define WW    56
#define POS   3136          // 56*56 = 49*64
#define QKVC  192
#define OC    64
#define SCALE 0.17677669529663687f   // 32^-0.5

typedef __attribute__((ext_vector_type(8))) short bf16x8;   // 8 bf16 = 4 VGPRs
typedef __attribute__((ext_vector_type(4))) float f32x4;

__device__ __forceinline__ unsigned short f2b(float f) {
    __hip_bfloat16 h = __float2bfloat16(f);
    union { __hip_bfloat16 h; unsigned short u; } c; c.h = h; return c.u;
}
__device__ __forceinline__ unsigned int pk(float lo, float hi) {
    return (unsigned int)f2b(lo) | ((unsigned int)f2b(hi) << 16);
}

// ---------------------------------------------------------------------------
// Kernel A: qkv = x @ qkv_w^T + qkv_b via bf16 MFMA, f[b][o][pos] fp32.
// Mtile=64 (49*64=3136 exact), Ntile=96, K=256 in 8 steps of 32.
// grid (49, 2, 16), 256 thr.
// ---------------------------------------------------------------------------
__global__ __launch_bounds__(256) void qkv_mfma(const float* __restrict__ x,
                                                const float* __restrict__ w,
                                                const float* __restrict__ bias,
                                                float* __restrict__ f) {
    __shared__ __align__(16) unsigned short wa[64 * 40];    // [m][k] rowstride 40 (80B)
    __shared__ __align__(16) unsigned short wb[96 * 264];   // [n][k] rowstride 264 (528B)
    const int tid = threadIdx.x;
    const int p0  = blockIdx.x * 64;
    const int o0  = blockIdx.y * 96;
    const int b   = blockIdx.z;

    // stage B once: w[o0+o][c], 96x256 fp32 -> bf16
    for (int idx = tid; idx < 96 * 64; idx += 256) {
        int o  = idx >> 6;
        int c4 = (idx & 63) << 2;
        const float4 t = *(const float4*)(w + (size_t)(o0 + o) * 256 + c4);
        *(unsigned int*)&wb[o * 264 + c4]     = pk(t.x, t.y);
        *(unsigned int*)&wb[o * 264 + c4 + 2] = pk(t.z, t.w);
    }

    f32x4 acc[6];
    #pragma unroll
    for (int u = 0; u < 6; ++u) acc[u] = (f32x4){0.f, 0.f, 0.f, 0.f};

    const int lane = tid & 63;
    const int wid  = tid >> 6;          // wave 0..3
    const int m0   = wid * 16;
    const int ml   = lane & 15;
    const int kg   = lane >> 4;         // 0..3

    const int c2 = (tid & 15) * 2;      // c-pair within k-step
    const int p4 = (tid >> 4) * 4;      // 4 pos per thread
    const float* xb = x + (size_t)b * 256 * POS;

    for (int ks = 0; ks < 8; ++ks) {
        const int c0 = ks * 32;
        __syncthreads();
        // stage A: transpose x[c0..c0+31][p0..p0+63] -> wa[p][c_local] bf16
        {
            const float4 r0 = *(const float4*)(xb + (size_t)(c0 + c2)     * POS + p0 + p4);
            const float4 r1 = *(const float4*)(xb + (size_t)(c0 + c2 + 1) * POS + p0 + p4);
            *(unsigned int*)&wa[(p4 + 0) * 40 + c2] = pk(r0.x, r1.x);
            *(unsigned int*)&wa[(p4 + 1) * 40 + c2] = pk(r0.y, r1.y);
            *(unsigned int*)&wa[(p4 + 2) * 40 + c2] = pk(r0.z, r1.z);
            *(unsigned int*)&wa[(p4 + 3) * 40 + c2] = pk(r0.w, r1.w);
        }
        __syncthreads();
        bf16x8 af = *(const bf16x8*)&wa[(m0 + ml) * 40 + kg * 8];
        #pragma unroll
        for (int u = 0; u < 6; ++u) {
            bf16x8 bf = *(const bf16x8*)&wb[(u * 16 + ml) * 264 + c0 + kg * 8];
            acc[u] = __builtin_amdgcn_mfma_f32_16x16x32_bf16(af, bf, acc[u], 0, 0, 0);
        }
    }

    // epilogue: D row=(kg*4+r)=pos offset, col=ml=o offset
    #pragma unroll
    for (int u = 0; u < 6; ++u) {
        int o = o0 + u * 16 + ml;
        float bj = bias[o];
        float4 st = { acc[u][0] + bj, acc[u][1] + bj, acc[u][2] + bj, acc[u][3] + bj };
        *(float4*)(f + ((size_t)b * QKVC + o) * POS + p0 + m0 + kg * 4) = st;
    }
}

// ---------------------------------------------------------------------------
// Kernel B: slide attention (fp32), coalesced fp32 output aout[b][oc][pos].
// grid (7, 8, 16), 448 thr.
// ---------------------------------------------------------------------------
#define TBH 8
__global__ __launch_bounds__(448) void attn_kernel(const float* __restrict__ f,
                                                   const float* __restrict__ dc_b,
                                                   const float* __restrict__ dc1_w,
                                                   const float* __restrict__ dc1_b,
                                                   const float* __restrict__ rpb,
                                                   float* __restrict__ aout) {
    __shared__ float kbuf[CH][TBH + 2][WW + 2];
    __shared__ float vbuf[CH][TBH + 2][WW + 2];
    __shared__ float wcp[CH * 9 * 12];

    const int tid = threadIdx.x;
    const int ty0 = blockIdx.x * TBH;
    const int h   = blockIdx.y;
    const int b   = blockIdx.z;
    const float* fb = f + ((size_t)b * QKVC + h * 24) * POS;

    const int HALO = (TBH + 2) * (WW + 2);   // 580
    for (int idx = tid; idx < 16 * HALO; idx += 448) {
        int c16 = idx / HALO;
        int rem = idx - c16 * HALO;
        int row = rem / (WW + 2);
        int col = rem - row * (WW + 2);
        int gy = ty0 + row - 1;
        int gx = col - 1;
        float val = 0.f;
        if (gy >= 0 && gy < HH && gx >= 0 && gx < WW) {
            int ch = c16 & 7;
            int o  = (c16 < 8) ? (8 + ch) : (16 + ch);
            val = fb[o * POS + gy * WW + gx];
        }
        float* dst = (c16 < 8) ? &kbuf[c16 & 7][0][0] : &vbuf[c16 & 7][0][0];
        dst[rem] = val;
    }
    for (int idx = tid; idx < 72; idx += 448) {
        int base = idx * 12;
        #pragma unroll
        for (int j = 0; j < 9; ++j) wcp[base + j] = dc1_w[idx * 9 + j];
        float db = dc_b[idx] + dc1_b[idx];
        int ka = idx % 9;
        wcp[base + 9]  = db + rpb[h * 9 + ka];
        wcp[base + 10] = db;
        wcp[base + 11] = 0.f;
    }
    __syncthreads();

    const int ly  = tid / WW;
    const int lx  = tid - ly * WW;
    const int pos = (ty0 + ly) * WW + lx;

    float q[CH];
    #pragma unroll
    for (int ch = 0; ch < CH; ++ch) q[ch] = fb[ch * POS + pos] * SCALE;

    float logits[9];
    #pragma unroll
    for (int ka = 0; ka < 9; ++ka) logits[ka] = 0.f;
    #pragma unroll
    for (int ch = 0; ch < CH; ++ch) {
        float n[9];
        #pragma unroll
        for (int dy = 0; dy < 3; ++dy)
            #pragma unroll
            for (int dx = 0; dx < 3; ++dx)
                n[dy * 3 + dx] = kbuf[ch][ly + dy][lx + dx];
        float qc = q[ch];
        const float4* wp = (const float4*)&wcp[ch * 108];
        #pragma unroll
        for (int ka = 0; ka < 9; ++ka) {
            float4 a4 = wp[ka * 3 + 0];
            float4 b4 = wp[ka * 3 + 1];
            float4 c4 = wp[ka * 3 + 2];
            float kv = n[ka] + c4.y;
            kv += n[0]*a4.x + n[1]*a4.y + n[2]*a4.z + n[3]*a4.w;
            kv += n[4]*b4.x + n[5]*b4.y + n[6]*b4.z + n[7]*b4.w;
            kv += n[8]*c4.x;
            logits[ka] += qc * kv;
        }
    }

    float m = logits[0];
    #pragma unroll
    for (int ka = 1; ka < 9; ++ka) m = fmaxf(m, logits[ka]);
    float att[9];
    float s = 0.f;
    #pragma unroll
    for (int ka = 0; ka < 9; ++ka) { att[ka] = __expf(logits[ka] - m); s += att[ka]; }
    float inv = 1.f / s;
    #pragma unroll
    for (int ka = 0; ka < 9; ++ka) att[ka] *= inv;

    float outv[CH];
    #pragma unroll
    for (int ch = 0; ch < CH; ++ch) {
        float n[9];
        #pragma unroll
        for (int dy = 0; dy < 3; ++dy)
            #pragma unroll
            for (int dx = 0; dx < 3; ++dx)
                n[dy * 3 + dx] = vbuf[ch][ly + dy][lx + dx];
        const float4* wp = (const float4*)&wcp[ch * 108];
        float o = 0.f;
        #pragma unroll
        for (int ka = 0; ka < 9; ++ka) {
            float4 a4 = wp[ka * 3 + 0];
            float4 b4 = wp[ka * 3 + 1];
            float4 c4 = wp[ka * 3 + 2];
            float vv = n[ka] + c4.z;
            vv += n[0]*a4.x + n[1]*a4.y + n[2]*a4.z + n[3]*a4.w;
            vv += n[4]*b4.x + n[5]*b4.y + n[6]*b4.z + n[7]*b4.w;
            vv += n[8]*c4.x;
            o += att[ka] * vv;
        }
        outv[ch] = o;
    }

    // coalesced fp32 store: aout[b][h*8+ch][pos], single-writer full lines
    float* ap = aout + ((size_t)b * OC + h * CH) * POS + pos;
    #pragma unroll
    for (int ch = 0; ch < CH; ++ch) ap[ch * POS] = outv[ch];
}

// ---------------------------------------------------------------------------
// Kernel C: out = a @ proj_w^T + proj_b via bf16 MFMA, fp32 NCHW out.
// A-stage does the [ch][pos] -> [m=pos][k=ch] transpose (fp32 -> bf16 pack).
// Mtile=64, Ntile=128, K=64 (2 mfma k-steps). grid (49, 2, 16)
// ---------------------------------------------------------------------------
__global__ __launch_bounds__(256) void proj_mfma(const float* __restrict__ a,
                                                 const float* __restrict__ w,
                                                 const float* __restrict__ bias,
                                                 float* __restrict__ out) {
    __shared__ __align__(16) unsigned short wa[64 * 72];    // [m][k] rowstride 72 (144B)
    __shared__ __align__(16) unsigned short wb[128 * 72];   // [n][k]
    const int tid = threadIdx.x;
    const int p0  = blockIdx.x * 64;
    const int o0  = blockIdx.y * 128;
    const int b   = blockIdx.z;

    // stage A with transpose: a[b][ch][p0+p] fp32 -> wa[p][ch] bf16
    {
        const int c2 = (tid & 31) * 2;       // ch pair 0..62
        const int p8 = (tid >> 5) * 8;       // 8 pos per thread
        const float* ab = a + (size_t)b * OC * POS + p0;
        const float4 r0a = *(const float4*)(ab + (size_t)c2 * POS + p8);
        const float4 r0b = *(const float4*)(ab + (size_t)c2 * POS + p8 + 4);
        const float4 r1a = *(const float4*)(ab + (size_t)(c2 + 1) * POS + p8);
        const float4 r1b = *(const float4*)(ab + (size_t)(c2 + 1) * POS + p8 + 4);
        *(unsigned int*)&wa[(p8 + 0) * 72 + c2] = pk(r0a.x, r1a.x);
        *(unsigned int*)&wa[(p8 + 1) * 72 + c2] = pk(r0a.y, r1a.y);
        *(unsigned int*)&wa[(p8 + 2) * 72 + c2] = pk(r0a.z, r1a.z);
        *(unsigned int*)&wa[(p8 + 3) * 72 + c2] = pk(r0a.w, r1a.w);
        *(unsigned int*)&wa[(p8 + 4) * 72 + c2] = pk(r0b.x, r1b.x);
        *(unsigned int*)&wa[(p8 + 5) * 72 + c2] = pk(r0b.y, r1b.y);
        *(unsigned int*)&wa[(p8 + 6) * 72 + c2] = pk(r0b.z, r1b.z);
        *(unsigned int*)&wa[(p8 + 7) * 72 + c2] = pk(r0b.w, r1b.w);
    }
    // stage B: proj_w[o0+o][ch] 128x64 fp32 -> bf16
    for (int idx = tid; idx < 2048; idx += 256) {
        int o = idx >> 4, c4 = (idx & 15) << 2;
        const float4 t = *(const float4*)(w + (size_t)(o0 + o) * 64 + c4);
        *(unsigned int*)&wb[o * 72 + c4]     = pk(t.x, t.y);
        *(unsigned int*)&wb[o * 72 + c4 + 2] = pk(t.z, t.w);
    }
    __syncthreads();

    const int lane = tid & 63;
    const int wid  = tid >> 6;
    const int m0   = wid * 16;
    const int ml   = lane & 15;
    const int kg   = lane >> 4;

    f32x4 acc[8];
    #pragma unroll
    for (int u = 0; u < 8; ++u) acc[u] = (f32x4){0.f, 0.f, 0.f, 0.f};

    #pragma unroll
    for (int s = 0; s < 2; ++s) {
        bf16x8 af = *(const bf16x8*)&wa[(m0 + ml) * 72 + s * 32 + kg * 8];
        #pragma unroll
        for (int u = 0; u < 8; ++u) {
            bf16x8 bf = *(const bf16x8*)&wb[(u * 16 + ml) * 72 + s * 32 + kg * 8];
            acc[u] = __builtin_amdgcn_mfma_f32_16x16x32_bf16(af, bf, acc[u], 0, 0, 0);
        }
    }

    #pragma unroll
    for (int u = 0; u < 8; ++u) {
        int o = o0 + u * 16 + ml;
        float bj = bias[o];
        float4 st = { acc[u][0] + bj, acc[u][1] + bj, acc[u][2] + bj, acc[u][3] + bj };
        *(float4*)(out + ((size_t)b * 256 + o) * POS + p0 + m0 + kg * 4) = st;
    }
}

// ---------------------------------------------------------------------------
extern "C" void kernel_launch(void* const* d_in, const int* in_sizes, int n_in,
                              void* d_out, int out_size, void* d_ws, size_t ws_size,
                              hipStream_t stream) {
    const float* x      = (const float*)d_in[0];
    const float* qkv_w  = (const float*)d_in[1];
    const float* qkv_b  = (const float*)d_in[2];
    const float* dc_b   = (const float*)d_in[3];
    const float* dc1_w  = (const float*)d_in[4];
    const float* dc1_b  = (const float*)d_in[5];
    const float* rpb    = (const float*)d_in[6];
    const float* proj_w = (const float*)d_in[7];
    const float* proj_b = (const float*)d_in[8];
    float* out = (float*)d_out;

    // ws: f fp32 38.5 MB + a fp32 12.8 MB
    float* f = (float*)d_ws;
    float* a = f + (size_t)BATCH * QKVC * POS;

    qkv_mfma<<<dim3(49, 2, BATCH), 256, 0, stream>>>(x, qkv_w, qkv_b, f);
    attn_kernel<<<dim3(7, NH, BATCH), 448, 0, stream>>>(f, dc_b, dc1_w, dc1_b, rpb, a);
    proj_mfma<<<dim3(49, 2, BATCH), 256, 0, stream>>>(a, proj_w, proj_b, out);
}